// Round 1
// baseline (21322.870 us; speedup 1.0000x reference)
//
#include <hip/hip_runtime.h>
#include <math.h>

// ---------------------------------------------------------------------------
// CDDD decoder: 3-layer GRU (512/1024/2048) greedy autoregressive decode.
// B=64 (lane = batch), 64 steps. fp32 throughout, token-exact target.
//
// Activations (h per layer, z^T) live in d_ws in "T4" layout:
//   buf[(k4*64 + b)*4 + c]  == value[b][k4*4+c]   (k4 = k/4, c = k%4)
// so a wave (lane=b) reads float4 at index (k4*64+b): fully coalesced 1KB/wave,
// while weight rows are wave-uniform float4 broadcasts.
// ---------------------------------------------------------------------------

#define BATCH 64

__device__ __forceinline__ void fma4(float& acc, const float4 w, const float4 x) {
    acc = fmaf(w.x, x.x, acc);
    acc = fmaf(w.y, x.y, acc);
    acc = fmaf(w.z, x.z, acc);
    acc = fmaf(w.w, x.w, acc);
}

__device__ __forceinline__ float sigmoid_f(float x) {
    return 1.0f / (1.0f + expf(-x));
}

// Transpose z [64,512] -> zT4, and init dec[] with start token.
__global__ __launch_bounds__(256) void init_misc_kernel(
    const float* __restrict__ z, float* __restrict__ zT4,
    int* __restrict__ dec, const int* __restrict__ start_tok)
{
    int tid = blockIdx.x * 256 + threadIdx.x;   // 8192 threads: (b, k4)
    int b  = tid >> 7;                          // 64
    int k4 = tid & 127;                         // 128
    float4 v = ((const float4*)z)[b * 128 + k4];
    ((float4*)zT4)[k4 * 64 + b] = v;
    if (tid < BATCH) dec[tid] = start_tok[0];
}

// init_states = z @ fc_init_w.T + fc_init_b ; split into h0/h1/h2 (T4 layout).
__global__ __launch_bounds__(256) void init_h_kernel(
    const float* __restrict__ zT4, const float* __restrict__ w,
    const float* __restrict__ bias,
    float* __restrict__ h0, float* __restrict__ h1, float* __restrict__ h2)
{
    const int wave = threadIdx.x >> 6;
    const int b    = threadIdx.x & 63;
    const int r    = blockIdx.x * 4 + wave;      // 0..3583
    const float4* w4 = (const float4*)(w + (size_t)r * 512);
    const float4* z4 = (const float4*)zT4;
    float acc = 0.f;
    #pragma unroll 8
    for (int k = 0; k < 128; ++k) {
        fma4(acc, w4[k], z4[k * 64 + b]);
    }
    acc += bias[r];
    float* dst; int j;
    if (r < 512)       { dst = h0; j = r; }
    else if (r < 1536) { dst = h1; j = r - 512; }
    else               { dst = h2; j = r - 1536; }
    dst[(((j >> 2) * 64 + b) << 2) + (j & 3)] = acc;
}

// One GRU layer, one step. Wave = one output column j (all 64 batches).
// L0: x comes from emb[dec[b]] instead of xT4.
template<int IN, int H, bool L0>
__global__ __launch_bounds__(256) void gru_kernel(
    const float* __restrict__ xT4,
    const float* __restrict__ emb, const int* __restrict__ dec,
    const float* __restrict__ hT4_in, float* __restrict__ hT4_out,
    const float* __restrict__ w_ih, const float* __restrict__ w_hh,
    const float* __restrict__ b_ih, const float* __restrict__ b_hh)
{
    const int wave = threadIdx.x >> 6;
    const int b    = threadIdx.x & 63;
    const int j    = (blockIdx.x << 2) + wave;   // output column

    const float4* wr = (const float4*)(w_ih + (size_t)j * IN);
    const float4* wz = (const float4*)(w_ih + (size_t)(j + H) * IN);
    const float4* wn = (const float4*)(w_ih + (size_t)(j + 2 * H) * IN);

    float air = 0.f, aiz = 0.f, ain = 0.f;
    if (L0) {
        const int tok = dec[b];
        const float4* x4 = (const float4*)(emb + tok * 32);
        #pragma unroll
        for (int k = 0; k < IN / 4; ++k) {
            float4 x = x4[k];
            fma4(air, wr[k], x);
            fma4(aiz, wz[k], x);
            fma4(ain, wn[k], x);
        }
    } else {
        const float4* x4 = (const float4*)xT4;
        #pragma unroll 4
        for (int k = 0; k < IN / 4; ++k) {
            float4 x = x4[k * 64 + b];
            fma4(air, wr[k], x);
            fma4(aiz, wz[k], x);
            fma4(ain, wn[k], x);
        }
    }

    const float4* vr = (const float4*)(w_hh + (size_t)j * H);
    const float4* vz = (const float4*)(w_hh + (size_t)(j + H) * H);
    const float4* vn = (const float4*)(w_hh + (size_t)(j + 2 * H) * H);
    const float4* h4 = (const float4*)hT4_in;

    float ahr = 0.f, ahz = 0.f, ahn = 0.f;
    #pragma unroll 4
    for (int k = 0; k < H / 4; ++k) {
        float4 h = h4[k * 64 + b];
        fma4(ahr, vr[k], h);
        fma4(ahz, vz[k], h);
        fma4(ahn, vn[k], h);
    }

    const float hprev = hT4_in[(((j >> 2) * 64 + b) << 2) + (j & 3)];

    const float r  = sigmoid_f(air + b_ih[j]         + ahr + b_hh[j]);
    const float zg = sigmoid_f(aiz + b_ih[j + H]     + ahz + b_hh[j + H]);
    const float n  = tanhf    (ain + b_ih[j + 2 * H] + r * (ahn + b_hh[j + 2 * H]));
    const float hn = (1.0f - zg) * n + zg * hprev;

    hT4_out[(((j >> 2) * 64 + b) << 2) + (j & 3)] = hn;
}

// logits[v][b] = dot(h2[.,b], fc_out_w[v,:])  — block = one vocab entry,
// 4 waves split the k range, LDS reduce.
__global__ __launch_bounds__(256) void logits_kernel(
    const float* __restrict__ h2T4, const float* __restrict__ w_out,
    float* __restrict__ logits)
{
    __shared__ float red[4][64];
    const int wave = threadIdx.x >> 6;
    const int b    = threadIdx.x & 63;
    const int v    = blockIdx.x;
    const float4* w4 = (const float4*)(w_out + (size_t)v * 2048);
    const float4* h4 = (const float4*)h2T4;
    float acc = 0.f;
    const int k0 = wave * 128, k1 = k0 + 128;
    #pragma unroll 4
    for (int k = k0; k < k1; ++k) {
        fma4(acc, w4[k], h4[k * 64 + b]);
    }
    red[wave][b] = acc;
    __syncthreads();
    if (wave == 0) {
        logits[v * 64 + b] = red[0][b] + red[1][b] + red[2][b] + red[3][b];
    }
}

// argmax over 40 vocab entries per batch row; first-max wins (matches jnp.argmax).
__global__ void argmax_kernel(const float* __restrict__ logits,
                              int* __restrict__ dec, int* __restrict__ out,
                              int s, int max_len)
{
    int b = threadIdx.x;
    if (b < BATCH) {
        float best = logits[b];
        int bi = 0;
        #pragma unroll
        for (int v = 1; v < 40; ++v) {
            float val = logits[v * 64 + b];
            if (val > best) { best = val; bi = v; }
        }
        dec[b] = bi;
        out[b * max_len + s] = bi;
    }
}

extern "C" void kernel_launch(void* const* d_in, const int* in_sizes, int n_in,
                              void* d_out, int out_size, void* d_ws, size_t ws_size,
                              hipStream_t stream)
{
    const float* z         = (const float*)d_in[0];
    const float* emb       = (const float*)d_in[1];
    const float* fc_init_w = (const float*)d_in[2];
    const float* fc_init_b = (const float*)d_in[3];
    const float* fc_out_w  = (const float*)d_in[4];
    const float* w_ih0 = (const float*)d_in[5];
    const float* w_hh0 = (const float*)d_in[6];
    const float* b_ih0 = (const float*)d_in[7];
    const float* b_hh0 = (const float*)d_in[8];
    const float* w_ih1 = (const float*)d_in[9];
    const float* w_hh1 = (const float*)d_in[10];
    const float* b_ih1 = (const float*)d_in[11];
    const float* b_hh1 = (const float*)d_in[12];
    const float* w_ih2 = (const float*)d_in[13];
    const float* w_hh2 = (const float*)d_in[14];
    const float* b_ih2 = (const float*)d_in[15];
    const float* b_hh2 = (const float*)d_in[16];
    const int* start_tok = (const int*)d_in[18];

    // workspace layout (bytes)
    char* ws = (char*)d_ws;
    float* zT4   = (float*)(ws + 0);                                  // 512*64*4 = 128KB
    float* h0b[2] = { (float*)(ws + 131072), (float*)(ws + 262144) }; // 128KB each
    float* h1b[2] = { (float*)(ws + 393216), (float*)(ws + 655360) }; // 256KB each
    float* h2b[2] = { (float*)(ws + 917504), (float*)(ws + 1441792) };// 512KB each
    float* logits = (float*)(ws + 1966080);                           // 40*64*4
    int*   dec    = (int*)(ws + 1976320);                             // 64*4

    int* out = (int*)d_out;
    const int max_len = out_size / BATCH;   // 64

    init_misc_kernel<<<32, 256, 0, stream>>>(z, zT4, dec, start_tok);
    init_h_kernel<<<896, 256, 0, stream>>>(zT4, fc_init_w, fc_init_b,
                                           h0b[0], h1b[0], h2b[0]);

    for (int s = 0; s < max_len; ++s) {
        const int pi = s & 1, po = pi ^ 1;
        gru_kernel<32, 512, true><<<128, 256, 0, stream>>>(
            nullptr, emb, dec, h0b[pi], h0b[po], w_ih0, w_hh0, b_ih0, b_hh0);
        gru_kernel<512, 1024, false><<<256, 256, 0, stream>>>(
            h0b[po], nullptr, nullptr, h1b[pi], h1b[po], w_ih1, w_hh1, b_ih1, b_hh1);
        gru_kernel<1024, 2048, false><<<512, 256, 0, stream>>>(
            h1b[po], nullptr, nullptr, h2b[pi], h2b[po], w_ih2, w_hh2, b_ih2, b_hh2);
        logits_kernel<<<40, 256, 0, stream>>>(h2b[po], fc_out_w, logits);
        argmax_kernel<<<1, 64, 0, stream>>>(logits, dec, out, s, max_len);
    }
}

// Round 3
// 14138.228 us; speedup vs baseline: 1.5082x; 1.5082x over previous
//
#include <hip/hip_runtime.h>
#include <math.h>

// ---------------------------------------------------------------------------
// CDDD decoder: 3-layer GRU (512/1024/2048) greedy autoregressive decode.
// B=64 (lane = batch), 64 steps, fp32, token-exact target.
//
// Activations in "T4" layout: buf[(k4*64+b)*4+c] == value[b][k4*4+c]
// -> wave (lane=b) reads float4 at quad index (k4*64+b): coalesced 1KB/wave.
//
// GRU kernel v2: block = 512 threads (8 waves) owns C output columns (all 3
// gates); the 8 waves split the concatenated K=(IN+H) range; LDS reduce;
// gate math + h-write fused. Weight loads are wave-uniform (scalar path).
//
// out_kernel: 512 threads (8 waves x 5 vocab rows) — round-2 bug was
// launching this with 256 threads, leaving lg[20..39] uninitialized.
// ---------------------------------------------------------------------------

#define BATCH 64

__device__ __forceinline__ void fma4(float& acc, const float4 w, const float4 x) {
    acc = fmaf(w.x, x.x, acc);
    acc = fmaf(w.y, x.y, acc);
    acc = fmaf(w.z, x.z, acc);
    acc = fmaf(w.w, x.w, acc);
}

__device__ __forceinline__ float sigmoid_f(float x) {
    return 1.0f / (1.0f + expf(-x));
}

// Transpose z [64,512] -> zT4, and init dec[] with start token.
__global__ __launch_bounds__(256) void init_misc_kernel(
    const float* __restrict__ z, float* __restrict__ zT4,
    int* __restrict__ dec, const int* __restrict__ start_tok)
{
    int tid = blockIdx.x * 256 + threadIdx.x;   // 8192 threads: (b, k4)
    int b  = tid >> 7;                          // 64
    int k4 = tid & 127;                         // 128
    float4 v = ((const float4*)z)[b * 128 + k4];
    ((float4*)zT4)[k4 * 64 + b] = v;
    if (tid < BATCH) dec[tid] = start_tok[0];
}

// init_states = z @ fc_init_w.T + fc_init_b ; split into h0/h1/h2 (T4 layout).
__global__ __launch_bounds__(256) void init_h_kernel(
    const float* __restrict__ zT4, const float* __restrict__ w,
    const float* __restrict__ bias,
    float* __restrict__ h0, float* __restrict__ h1, float* __restrict__ h2)
{
    const int wave = threadIdx.x >> 6;
    const int b    = threadIdx.x & 63;
    const int r    = blockIdx.x * 4 + wave;      // 0..3583
    const float4* w4 = (const float4*)(w + (size_t)r * 512);
    const float4* z4 = (const float4*)zT4;
    float acc = 0.f;
    #pragma unroll 8
    for (int k = 0; k < 128; ++k) {
        fma4(acc, w4[k], z4[k * 64 + b]);
    }
    acc += bias[r];
    float* dst; int j;
    if (r < 512)       { dst = h0; j = r; }
    else if (r < 1536) { dst = h1; j = r - 512; }
    else               { dst = h2; j = r - 1536; }
    dst[(((j >> 2) * 64 + b) << 2) + (j & 3)] = acc;
}

// GRU layer step, v2.
// Block: 512 threads = 8 waves. Block owns C columns j0..j0+C-1 (3 gates each).
// Waves split the concatenated quad range [0, (IN+H)/4).
template<int IN, int H, int C, bool L0>
__global__ __launch_bounds__(512) void gru2_kernel(
    const float* __restrict__ xT4,
    const float* __restrict__ emb, const int* __restrict__ dec,
    const float* __restrict__ hT4_in, float* __restrict__ hT4_out,
    const float* __restrict__ w_ih, const float* __restrict__ w_hh,
    const float* __restrict__ b_ih, const float* __restrict__ b_hh)
{
    constexpr int Q  = (IN + H) / 4;   // total quads
    constexpr int QX = IN / 4;         // x-region quads
    constexpr int QW = Q / 8;          // quads per wave (divides exactly)

    const int tid  = threadIdx.x;
    const int wave = tid >> 6;
    const int b    = tid & 63;
    const int j0   = blockIdx.x * C;

    const int q0 = wave * QW;
    const int q1 = q0 + QW;

    float accR[C], accZ[C], accNX[C], accNH[C];
    #pragma unroll
    for (int c = 0; c < C; ++c) { accR[c] = 0.f; accZ[c] = 0.f; accNX[c] = 0.f; accNH[c] = 0.f; }

    // ---- x region: quads [q0, min(q1, QX)) ----
    {
        const int xe = (q1 < QX) ? q1 : QX;
        if (q0 < xe) {
            const float4* xsrc;
            if (L0) {
                const int tok = dec[b];
                xsrc = (const float4*)(emb + tok * 32);
            } else {
                xsrc = (const float4*)xT4;
            }
            for (int q = q0; q < xe; ++q) {
                const float4 x = L0 ? xsrc[q] : xsrc[q * 64 + b];
                #pragma unroll
                for (int c = 0; c < C; ++c) {
                    const int j = j0 + c;
                    const float4* wr = (const float4*)(w_ih + (size_t)j * IN);
                    const float4* wz = (const float4*)(w_ih + (size_t)(j + H) * IN);
                    const float4* wn = (const float4*)(w_ih + (size_t)(j + 2 * H) * IN);
                    fma4(accR[c],  wr[q], x);
                    fma4(accZ[c],  wz[q], x);
                    fma4(accNX[c], wn[q], x);
                }
            }
        }
    }

    // ---- h region: quads [max(q0, QX), q1), h-quad index qh = q - QX ----
    {
        const int hs0 = (q0 > QX) ? q0 : QX;
        if (hs0 < q1) {
            const float4* h4 = (const float4*)hT4_in;
            #pragma unroll 2
            for (int q = hs0; q < q1; ++q) {
                const int qh = q - QX;
                const float4 h = h4[qh * 64 + b];
                #pragma unroll
                for (int c = 0; c < C; ++c) {
                    const int j = j0 + c;
                    const float4* vr = (const float4*)(w_hh + (size_t)j * H);
                    const float4* vz = (const float4*)(w_hh + (size_t)(j + H) * H);
                    const float4* vn = (const float4*)(w_hh + (size_t)(j + 2 * H) * H);
                    fma4(accR[c],  vr[qh], h);
                    fma4(accZ[c],  vz[qh], h);
                    fma4(accNH[c], vn[qh], h);
                }
            }
        }
    }

    // ---- LDS reduce across the 8 waves ----
    __shared__ float red[8][C][4][64];
    #pragma unroll
    for (int c = 0; c < C; ++c) {
        red[wave][c][0][b] = accR[c];
        red[wave][c][1][b] = accZ[c];
        red[wave][c][2][b] = accNX[c];
        red[wave][c][3][b] = accNH[c];
    }
    __syncthreads();

    if (tid < C * 64) {
        const int c  = tid >> 6;
        const int bb = tid & 63;
        float R = 0.f, Z = 0.f, NX = 0.f, NH = 0.f;
        #pragma unroll
        for (int w = 0; w < 8; ++w) {
            R  += red[w][c][0][bb];
            Z  += red[w][c][1][bb];
            NX += red[w][c][2][bb];
            NH += red[w][c][3][bb];
        }
        const int j = j0 + c;
        const float r  = sigmoid_f(R + b_ih[j]     + b_hh[j]);
        const float zg = sigmoid_f(Z + b_ih[j + H] + b_hh[j + H]);
        const float n  = tanhf(NX + b_ih[j + 2 * H] + r * (NH + b_hh[j + 2 * H]));
        const float hprev = hT4_in[(((j >> 2) * 64 + bb) << 2) + (j & 3)];
        hT4_out[(((j >> 2) * 64 + bb) << 2) + (j & 3)] = (1.0f - zg) * n + zg * hprev;
    }
}

// Fused logits + argmax: one block per batch element, 512 threads = 8 waves.
// Stage h2[b] (2048 f32 = 8KB) in LDS; 8 waves x 5 vocab rows each;
// lane-split K with shuffle reduce; thread 0 does the 40-way argmax.
__global__ __launch_bounds__(512) void out_kernel(
    const float* __restrict__ h2T4, const float* __restrict__ w_out,
    int* __restrict__ dec, int* __restrict__ out, int s, int max_len)
{
    __shared__ float hs[2048];
    __shared__ float lg[40];
    const int b    = blockIdx.x;
    const int tid  = threadIdx.x;
    const int wave = tid >> 6;    // 0..7
    const int lane = tid & 63;

    const float4* h4 = (const float4*)h2T4;
    ((float4*)hs)[tid] = h4[tid * 64 + b];    // 512 threads x 1 quad = 2048 f32
    __syncthreads();

    const float4* hs4 = (const float4*)hs;
    #pragma unroll
    for (int v = wave * 5; v < wave * 5 + 5; ++v) {
        const float4* w4 = (const float4*)(w_out + (size_t)v * 2048);
        float acc = 0.f;
        #pragma unroll
        for (int it = 0; it < 8; ++it) {
            const int k4 = it * 64 + lane;
            fma4(acc, w4[k4], hs4[k4]);
        }
        #pragma unroll
        for (int off = 32; off > 0; off >>= 1)
            acc += __shfl_down(acc, off, 64);
        if (lane == 0) lg[v] = acc;
    }
    __syncthreads();

    if (tid == 0) {
        float best = lg[0];
        int bi = 0;
        #pragma unroll
        for (int v = 1; v < 40; ++v) {
            const float val = lg[v];
            if (val > best) { best = val; bi = v; }
        }
        dec[b] = bi;
        out[b * max_len + s] = bi;
    }
}

extern "C" void kernel_launch(void* const* d_in, const int* in_sizes, int n_in,
                              void* d_out, int out_size, void* d_ws, size_t ws_size,
                              hipStream_t stream)
{
    const float* z         = (const float*)d_in[0];
    const float* emb       = (const float*)d_in[1];
    const float* fc_init_w = (const float*)d_in[2];
    const float* fc_init_b = (const float*)d_in[3];
    const float* fc_out_w  = (const float*)d_in[4];
    const float* w_ih0 = (const float*)d_in[5];
    const float* w_hh0 = (const float*)d_in[6];
    const float* b_ih0 = (const float*)d_in[7];
    const float* b_hh0 = (const float*)d_in[8];
    const float* w_ih1 = (const float*)d_in[9];
    const float* w_hh1 = (const float*)d_in[10];
    const float* b_ih1 = (const float*)d_in[11];
    const float* b_hh1 = (const float*)d_in[12];
    const float* w_ih2 = (const float*)d_in[13];
    const float* w_hh2 = (const float*)d_in[14];
    const float* b_ih2 = (const float*)d_in[15];
    const float* b_hh2 = (const float*)d_in[16];
    const int* start_tok = (const int*)d_in[18];

    // workspace layout (bytes)
    char* ws = (char*)d_ws;
    float* zT4    = (float*)(ws + 0);                                  // 128KB
    float* h0b[2] = { (float*)(ws + 131072), (float*)(ws + 262144) };  // 128KB each
    float* h1b[2] = { (float*)(ws + 393216), (float*)(ws + 655360) };  // 256KB each
    float* h2b[2] = { (float*)(ws + 917504), (float*)(ws + 1441792) }; // 512KB each
    int*   dec    = (int*)(ws + 1966080);

    int* out = (int*)d_out;
    const int max_len = out_size / BATCH;   // 64

    init_misc_kernel<<<32, 256, 0, stream>>>(z, zT4, dec, start_tok);
    init_h_kernel<<<896, 256, 0, stream>>>(zT4, fc_init_w, fc_init_b,
                                           h0b[0], h1b[0], h2b[0]);

    for (int s = 0; s < max_len; ++s) {
        const int pi = s & 1, po = pi ^ 1;
        // L0: 512 cols / C=2 -> 256 blocks
        gru2_kernel<32, 512, 2, true><<<256, 512, 0, stream>>>(
            nullptr, emb, dec, h0b[pi], h0b[po], w_ih0, w_hh0, b_ih0, b_hh0);
        // L1: 1024 cols / C=4 -> 256 blocks
        gru2_kernel<512, 1024, 4, false><<<256, 512, 0, stream>>>(
            h0b[po], nullptr, nullptr, h1b[pi], h1b[po], w_ih1, w_hh1, b_ih1, b_hh1);
        // L2: 2048 cols / C=4 -> 512 blocks
        gru2_kernel<1024, 2048, 4, false><<<512, 512, 0, stream>>>(
            h1b[po], nullptr, nullptr, h2b[pi], h2b[po], w_ih2, w_hh2, b_ih2, b_hh2);
        // logits + argmax fused: 64 blocks (one per batch row), 512 threads
        out_kernel<<<64, 512, 0, stream>>>(h2b[po], fc_out_w, dec, out, s, max_len);
    }
}